// Round 9
// baseline (597.519 us; speedup 1.0000x reference)
//
#include <hip/hip_runtime.h>

#define N_SRC   100000
#define N_TGT   50000
#define N_EDGES 1000000
#define NEG     0.2
#define NXCD    8
#define TPART   (N_TGT / NXCD)   // 6250
#define SPART   (N_SRC / NXCD)   // 12500

// ===========================================================================
// CSR/CSC build + gather. Edge-score math in f64 (ill-conditioned row sums);
// msg matrices f32 (bf16 fatal, R6). Scatter/hist XCD-partitioned (R8: -120us).
// GEMM col-split x4 for occupancy (R8: rowlane was 1.5 waves/SIMD).
// ===========================================================================

// ---------------------------------------------------------------------------
// GEMM: msg = x @ w (K=128, N=64). Block = 64 rows x 4 waves; wave 'part'
// owns cols [part*16, part*16+16). Lane = row. w addresses wave-uniform ->
// s_load; acc[16] in VGPRs; 6+ waves/SIMD hides scalar-load latency.
// Per-column FMA order identical to R3/R8 rowlane -> msg bit-identical.
// evec combined across parts via fixed-order LDS f64 reduce.
// ---------------------------------------------------------------------------
__global__ __launch_bounds__(256) void gemm_part4(
    const float* __restrict__ x, const float* __restrict__ w,
    const float* __restrict__ att, int att_off, int nrows,
    float* __restrict__ msg, double* __restrict__ evec)
{
    const int lane = threadIdx.x & 63;
    const int part = threadIdx.x >> 6;       // 0..3, wave-uniform
    const int row0 = blockIdx.x * 64;
    const int row  = row0 + lane;
    const bool act = row < nrows;
    const float* xr = x + (size_t)row * 128;
    const int c0 = part * 16;

    float acc[16];
    #pragma unroll
    for (int c = 0; c < 16; ++c) acc[c] = 0.f;

    for (int kc = 0; kc < 128; kc += 16) {    // 8 chunks
        float4 xv[4];
        #pragma unroll
        for (int q = 0; q < 4; ++q)
            xv[q] = act ? *(const float4*)(xr + kc + 4 * q)
                        : make_float4(0.f, 0.f, 0.f, 0.f);
        #pragma unroll
        for (int kk = 0; kk < 16; ++kk) {
            const float xk = ((const float*)xv)[kk];
            const float* wr = w + (size_t)(kc + kk) * 64 + c0;  // wave-uniform
            #pragma unroll
            for (int c = 0; c < 16; ++c)
                acc[c] = fmaf(xk, wr[c], acc[c]);
        }
    }

    // evec partial dot (f64), combine across the 4 parts in fixed order
    double e = 0.0;
    #pragma unroll
    for (int c = 0; c < 16; ++c)
        e += (double)acc[c] * (double)att[att_off + c0 + c];

    __shared__ double eds[4][64];
    eds[part][lane] = e;
    __syncthreads();
    if (part == 0 && act)
        evec[row] = eds[0][lane] + eds[1][lane] + eds[2][lane] + eds[3][lane];

    if (act) {
        float* mo = msg + (size_t)row * 64 + c0;
        #pragma unroll
        for (int q = 0; q < 4; ++q)
            *(float4*)(mo + 4 * q) = *(float4*)(acc + 4 * q);
    }
}

// ---------------------------------------------------------------------------
// Histogram, XCD-partitioned (R8-proven).
// ---------------------------------------------------------------------------
__global__ __launch_bounds__(256) void hist_part(
    const int* __restrict__ rows, const int* __restrict__ cols,
    int* __restrict__ cnt_r, int* __restrict__ cnt_c)
{
    const int xcd  = blockIdx.x & (NXCD - 1);
    const int ibx  = blockIdx.x >> 3;
    const int step = (gridDim.x >> 3) * blockDim.x;
    const int lo_r = xcd * TPART, lo_c = xcd * SPART;

    for (int i = ibx * blockDim.x + threadIdx.x; i < N_EDGES; i += step) {
        const int r = rows[i], c = cols[i];
        if ((unsigned)(r - lo_r) < TPART) atomicAdd(&cnt_r[r], 1);
        if ((unsigned)(c - lo_c) < SPART) atomicAdd(&cnt_c[c], 1);
    }
}

// ---------------------------------------------------------------------------
// Exclusive scan, tiled + coalesced. block 0 -> rows (N_TGT), 1 -> cols (N_SRC).
// ---------------------------------------------------------------------------
__global__ __launch_bounds__(1024) void scan_two(
    const int* __restrict__ cnt_r, const int* __restrict__ cnt_c,
    int* __restrict__ ptr_r, int* __restrict__ ofs_r,
    int* __restrict__ ptr_c, int* __restrict__ ofs_c)
{
    const int n    = blockIdx.x ? N_SRC : N_TGT;
    const int* cnt = blockIdx.x ? cnt_c : cnt_r;
    int* ptr       = blockIdx.x ? ptr_c : ptr_r;
    int* ofs       = blockIdx.x ? ofs_c : ofs_r;
    const int tid  = threadIdx.x;
    const int lane = tid & 63, wid = tid >> 6;

    __shared__ int wsum[16];
    __shared__ int s_carry;
    if (tid == 0) s_carry = 0;
    __syncthreads();

    for (int base = 0; base < n; base += 4096) {
        const int idx = base + tid * 4;
        int4 v = make_int4(0, 0, 0, 0);
        if (idx + 3 < n) {
            v = *(const int4*)(cnt + idx);
        } else if (idx < n) {
            v.x = cnt[idx];
            if (idx + 1 < n) v.y = cnt[idx + 1];
            if (idx + 2 < n) v.z = cnt[idx + 2];
        }
        const int s = v.x + v.y + v.z + v.w;

        int p = s;
        #pragma unroll
        for (int d = 1; d < 64; d <<= 1) {
            int t = __shfl_up(p, d);
            if (lane >= d) p += t;
        }
        if (lane == 63) wsum[wid] = p;
        __syncthreads();
        if (tid == 0) {
            int a = 0;
            #pragma unroll
            for (int i = 0; i < 16; ++i) { int t = wsum[i]; wsum[i] = a; a += t; }
        }
        __syncthreads();

        int run = s_carry + wsum[wid] + (p - s);
        if (idx     < n) { ptr[idx]     = run; ofs[idx]     = run; } run += v.x;
        if (idx + 1 < n) { ptr[idx + 1] = run; ofs[idx + 1] = run; } run += v.y;
        if (idx + 2 < n) { ptr[idx + 2] = run; ofs[idx + 2] = run; } run += v.z;
        if (idx + 3 < n) { ptr[idx + 3] = run; ofs[idx + 3] = run; } run += v.w;

        __syncthreads();
        if (tid == 1023) s_carry = run;
        __syncthreads();
    }
    if (tid == 0) ptr[n] = s_carry;
}

// ---------------------------------------------------------------------------
// Scatter, XCD-partitioned (R8-proven: WRITE_SIZE 126->~25 MB).
// ---------------------------------------------------------------------------
__global__ __launch_bounds__(256) void scatter_part(
    const int* __restrict__ rows, const int* __restrict__ cols,
    const float* __restrict__ nbhd,
    int* __restrict__ ofs_r, int* __restrict__ ofs_c,
    unsigned long long* __restrict__ srtT, unsigned long long* __restrict__ srtS)
{
    const int xcd  = blockIdx.x & (NXCD - 1);
    const int ibx  = blockIdx.x >> 3;
    const int step = (gridDim.x >> 3) * blockDim.x;
    const int lo_r = xcd * TPART, lo_c = xcd * SPART;

    for (int i = ibx * blockDim.x + threadIdx.x; i < N_EDGES; i += step) {
        const int r = rows[i], c = cols[i];
        const bool mr = (unsigned)(r - lo_r) < TPART;
        const bool mc = (unsigned)(c - lo_c) < SPART;
        if (!(mr | mc)) continue;
        const unsigned long long nb =
            (unsigned long long)(unsigned)__float_as_int(nbhd[i]) << 32;
        if (mr) { const int p = atomicAdd(&ofs_r[r], 1); srtT[p] = nb | (unsigned)c; }
        if (mc) { const int q = atomicAdd(&ofs_c[c], 1); srtS[q] = nb | (unsigned)r; }
    }
}

// ---------------------------------------------------------------------------
// Gather: one wave per output row, lane = feature. Scores recomputed in f64
// from es_d/et_d (1.2 MB, L2-resident); den/acc in f64; msg f32.
// ---------------------------------------------------------------------------
__global__ __launch_bounds__(256) void gather_both(
    const int2* __restrict__ srtT, const int* __restrict__ ptr_r,
    const float* __restrict__ s_msg, float* __restrict__ msg_tgt,
    const int2* __restrict__ srtS, const int* __restrict__ ptr_c,
    const float* __restrict__ t_msg, float* __restrict__ msg_src,
    const double* __restrict__ es_d, const double* __restrict__ et_d)
{
    const int gw   = (blockIdx.x * blockDim.x + threadIdx.x) >> 6;
    const int lane = threadIdx.x & 63;

    const int2* srt; const int* ptr; const float* min_; float* out;
    const double* other_d; double base; int row;
    if (gw < N_TGT) {
        srt = srtT; ptr = ptr_r; min_ = s_msg; out = msg_tgt;
        other_d = es_d; row = gw; base = et_d[row];
    } else {
        row = gw - N_TGT;
        if (row >= N_SRC) return;
        srt = srtS; ptr = ptr_c; min_ = t_msg; out = msg_src;
        other_d = et_d; base = es_d[row];
    }

    const int b = ptr[row], e = ptr[row + 1];
    double den = 0.0, acc = 0.0;

    for (int j0 = b; j0 < e; j0 += 64) {
        const int m = e - j0;
        int oidx = 0; double v = 0.0; float wf = 0.f;
        if (lane < m) {
            const int2 pay = srt[j0 + lane];
            oidx = pay.x;
            const float nb = __int_as_float(pay.y);
            const double sv = base + other_d[oidx];
            v = (sv >= 0.0) ? sv : NEG * sv;
            wf = (float)(v * (double)nb);
        }
        den += v;

        const int cnt = m < 64 ? m : 64;
        for (int j = 0; j < cnt; ++j) {
            const int   c = __shfl(oidx, j);
            const float w = __shfl(wf, j);
            acc += (double)w * (double)min_[(size_t)c * 64 + lane];
        }
    }
    #pragma unroll
    for (int s = 32; s; s >>= 1) den += __shfl_xor(den, s);
    const double inv = (den != 0.0) ? 1.0 / den : 0.0;
    out[(size_t)row * 64 + lane] = (float)(acc * inv);
}

// ===========================================================================
extern "C" void kernel_launch(void* const* d_in, const int* in_sizes, int n_in,
                              void* d_out, int out_size, void* d_ws, size_t ws_size,
                              hipStream_t stream)
{
    const float* x_source = (const float*)d_in[0];
    const float* x_target = (const float*)d_in[1];
    const float* w_s      = (const float*)d_in[2];
    const float* w_t      = (const float*)d_in[3];
    const float* att      = (const float*)d_in[4];
    const float* nbhd     = (const float*)d_in[5];
    const int*   rows     = (const int*)d_in[6];
    const int*   cols     = (const int*)d_in[7];

    float* out     = (float*)d_out;
    float* msg_src = out;                       // (N_SRC, 64)
    float* msg_tgt = out + (size_t)N_SRC * 64;  // (N_TGT, 64)

    char* ws = (char*)d_ws;
    // byte layout: total 57,400,016 B
    float*  s_msg = (float*) (ws + 0);           // 25,600,000
    float*  t_msg = (float*) (ws + 25600000);    // 12,800,000
    double* es_d  = (double*)(ws + 38400000);    //    800,000
    double* et_d  = (double*)(ws + 39200000);    //    400,000
    int*    cnt_r = (int*)   (ws + 39600000);    //    200,000
    int*    cnt_c = (int*)   (ws + 39800000);    //    400,000
    int*    ptr_r = (int*)   (ws + 40200000);    //    200,004
    int*    ptr_c = (int*)   (ws + 40400004);    //    400,004
    int*    ofs_r = (int*)   (ws + 40800008);    //    200,000
    int*    ofs_c = (int*)   (ws + 41000008);    //    400,000 (+8 pad)
    unsigned long long* srtT = (unsigned long long*)(ws + 41400016); // 8,000,000
    unsigned long long* srtS = (unsigned long long*)(ws + 49400016); // 8,000,000

    hipMemsetAsync(ws + 39600000, 0, 600000, stream);  // cnt_r + cnt_c

    gemm_part4<<<(N_SRC + 63) / 64, 256, 0, stream>>>(
        x_source, w_s, att, 0, N_SRC, s_msg, es_d);
    gemm_part4<<<(N_TGT + 63) / 64, 256, 0, stream>>>(
        x_target, w_t, att, 64, N_TGT, t_msg, et_d);

    hist_part<<<2048, 256, 0, stream>>>(rows, cols, cnt_r, cnt_c);
    scan_two<<<2, 1024, 0, stream>>>(cnt_r, cnt_c, ptr_r, ofs_r, ptr_c, ofs_c);
    scatter_part<<<2048, 256, 0, stream>>>(
        rows, cols, nbhd, ofs_r, ofs_c, srtT, srtS);

    gather_both<<<(N_TGT + N_SRC + 3) / 4, 256, 0, stream>>>(
        (const int2*)srtT, ptr_r, s_msg, msg_tgt,
        (const int2*)srtS, ptr_c, t_msg, msg_src, es_d, et_d);
}

// Round 10
// 568.552 us; speedup vs baseline: 1.0509x; 1.0509x over previous
//
#include <hip/hip_runtime.h>

#define N_SRC   100000
#define N_TGT   50000
#define N_EDGES 1000000
#define NEG     0.2
#define NXCD    8
#define TPART   (N_TGT / NXCD)   // 6250
#define SPART   (N_SRC / NXCD)   // 12500

// ===========================================================================
// CSR/CSC build + gather. Edge-score math in f64 (ill-conditioned row sums);
// msg matrices f32 (bf16 fatal, R6). Scatter/hist XCD-partitioned (R8-proven).
// GEMM: 4 column-waves fed from one LDS-staged x tile (fixes R9's 4x
// divergent re-read while keeping its occupancy).
// ===========================================================================

// ---------------------------------------------------------------------------
// GEMM: msg = x @ w (K=128, N=64). Block = 256 thr = 64 rows x 4 col-waves.
// x tile staged once, coalesced, into xs[64][129] (129%32==1 -> per-lane row
// reads are 2-way/free). Wave 'part' owns cols [16p,16p+16); w addresses
// wave-uniform -> s_load. acc[16]/lane; per-column FMA k-order identical to
// rowlane/part4 -> msg bit-identical, absmax must stay 1024.
// ---------------------------------------------------------------------------
#define XS 129
__global__ __launch_bounds__(256) void gemm_lds4(
    const float* __restrict__ x, const float* __restrict__ w,
    const float* __restrict__ att, int att_off, int nrows,
    float* __restrict__ msg, double* __restrict__ evec)
{
    __shared__ float xs[64 * XS];          // 33 KB
    __shared__ double eds[4][64];          //  2 KB
    const int tid  = threadIdx.x;
    const int lane = tid & 63;
    const int part = tid >> 6;             // 0..3, wave-uniform
    const int row0 = blockIdx.x * 64;
    const int row  = row0 + lane;
    const bool act = row < nrows;
    const int c0   = part * 16;

    // stage 64 rows x 128 f32: 2048 float4, 256 threads -> 8 iters, coalesced
    #pragma unroll
    for (int it = 0; it < 8; ++it) {
        const int fid = tid + it * 256;    // 0..2047
        const int r = fid >> 5, q = fid & 31;
        if (row0 + r < nrows) {
            const float4 v = *(const float4*)(x + (size_t)(row0 + r) * 128 + 4 * q);
            float* d = &xs[r * XS + 4 * q];
            d[0] = v.x; d[1] = v.y; d[2] = v.z; d[3] = v.w;
        }
    }
    __syncthreads();

    float acc[16];
    #pragma unroll
    for (int c = 0; c < 16; ++c) acc[c] = 0.f;

    const int xbase = lane * XS;
    for (int kc = 0; kc < 128; kc += 16) {     // 8 chunks
        #pragma unroll
        for (int kk = 0; kk < 16; ++kk) {
            const float xk = xs[xbase + kc + kk];
            const float* wr = w + (size_t)(kc + kk) * 64 + c0;  // wave-uniform
            #pragma unroll
            for (int c = 0; c < 16; ++c)
                acc[c] = fmaf(xk, wr[c], acc[c]);
        }
    }

    // evec partial dot (f64), combine across parts in fixed order (R9-proven)
    double e = 0.0;
    #pragma unroll
    for (int c = 0; c < 16; ++c)
        e += (double)acc[c] * (double)att[att_off + c0 + c];
    eds[part][lane] = e;
    __syncthreads();
    if (part == 0 && act)
        evec[row] = eds[0][lane] + eds[1][lane] + eds[2][lane] + eds[3][lane];

    if (act) {
        float* mo = msg + (size_t)row * 64 + c0;
        #pragma unroll
        for (int q = 0; q < 4; ++q)
            *(float4*)(mo + 4 * q) = *(float4*)(acc + 4 * q);
    }
}

// ---------------------------------------------------------------------------
// Histogram, XCD-partitioned (R8-proven).
// ---------------------------------------------------------------------------
__global__ __launch_bounds__(256) void hist_part(
    const int* __restrict__ rows, const int* __restrict__ cols,
    int* __restrict__ cnt_r, int* __restrict__ cnt_c)
{
    const int xcd  = blockIdx.x & (NXCD - 1);
    const int ibx  = blockIdx.x >> 3;
    const int step = (gridDim.x >> 3) * blockDim.x;
    const int lo_r = xcd * TPART, lo_c = xcd * SPART;

    for (int i = ibx * blockDim.x + threadIdx.x; i < N_EDGES; i += step) {
        const int r = rows[i], c = cols[i];
        if ((unsigned)(r - lo_r) < TPART) atomicAdd(&cnt_r[r], 1);
        if ((unsigned)(c - lo_c) < SPART) atomicAdd(&cnt_c[c], 1);
    }
}

// ---------------------------------------------------------------------------
// Exclusive scan, tiled + coalesced. block 0 -> rows (N_TGT), 1 -> cols (N_SRC).
// ---------------------------------------------------------------------------
__global__ __launch_bounds__(1024) void scan_two(
    const int* __restrict__ cnt_r, const int* __restrict__ cnt_c,
    int* __restrict__ ptr_r, int* __restrict__ ofs_r,
    int* __restrict__ ptr_c, int* __restrict__ ofs_c)
{
    const int n    = blockIdx.x ? N_SRC : N_TGT;
    const int* cnt = blockIdx.x ? cnt_c : cnt_r;
    int* ptr       = blockIdx.x ? ptr_c : ptr_r;
    int* ofs       = blockIdx.x ? ofs_c : ofs_r;
    const int tid  = threadIdx.x;
    const int lane = tid & 63, wid = tid >> 6;

    __shared__ int wsum[16];
    __shared__ int s_carry;
    if (tid == 0) s_carry = 0;
    __syncthreads();

    for (int base = 0; base < n; base += 4096) {
        const int idx = base + tid * 4;
        int4 v = make_int4(0, 0, 0, 0);
        if (idx + 3 < n) {
            v = *(const int4*)(cnt + idx);
        } else if (idx < n) {
            v.x = cnt[idx];
            if (idx + 1 < n) v.y = cnt[idx + 1];
            if (idx + 2 < n) v.z = cnt[idx + 2];
        }
        const int s = v.x + v.y + v.z + v.w;

        int p = s;
        #pragma unroll
        for (int d = 1; d < 64; d <<= 1) {
            int t = __shfl_up(p, d);
            if (lane >= d) p += t;
        }
        if (lane == 63) wsum[wid] = p;
        __syncthreads();
        if (tid == 0) {
            int a = 0;
            #pragma unroll
            for (int i = 0; i < 16; ++i) { int t = wsum[i]; wsum[i] = a; a += t; }
        }
        __syncthreads();

        int run = s_carry + wsum[wid] + (p - s);
        if (idx     < n) { ptr[idx]     = run; ofs[idx]     = run; } run += v.x;
        if (idx + 1 < n) { ptr[idx + 1] = run; ofs[idx + 1] = run; } run += v.y;
        if (idx + 2 < n) { ptr[idx + 2] = run; ofs[idx + 2] = run; } run += v.z;
        if (idx + 3 < n) { ptr[idx + 3] = run; ofs[idx + 3] = run; } run += v.w;

        __syncthreads();
        if (tid == 1023) s_carry = run;
        __syncthreads();
    }
    if (tid == 0) ptr[n] = s_carry;
}

// ---------------------------------------------------------------------------
// Scatter, XCD-partitioned (R8-proven: write-amp gone).
// ---------------------------------------------------------------------------
__global__ __launch_bounds__(256) void scatter_part(
    const int* __restrict__ rows, const int* __restrict__ cols,
    const float* __restrict__ nbhd,
    int* __restrict__ ofs_r, int* __restrict__ ofs_c,
    unsigned long long* __restrict__ srtT, unsigned long long* __restrict__ srtS)
{
    const int xcd  = blockIdx.x & (NXCD - 1);
    const int ibx  = blockIdx.x >> 3;
    const int step = (gridDim.x >> 3) * blockDim.x;
    const int lo_r = xcd * TPART, lo_c = xcd * SPART;

    for (int i = ibx * blockDim.x + threadIdx.x; i < N_EDGES; i += step) {
        const int r = rows[i], c = cols[i];
        const bool mr = (unsigned)(r - lo_r) < TPART;
        const bool mc = (unsigned)(c - lo_c) < SPART;
        if (!(mr | mc)) continue;
        const unsigned long long nb =
            (unsigned long long)(unsigned)__float_as_int(nbhd[i]) << 32;
        if (mr) { const int p = atomicAdd(&ofs_r[r], 1); srtT[p] = nb | (unsigned)c; }
        if (mc) { const int q = atomicAdd(&ofs_c[c], 1); srtS[q] = nb | (unsigned)r; }
    }
}

// ---------------------------------------------------------------------------
// Gather: one wave per output row, lane = feature. Scores recomputed in f64
// from es_d/et_d (L2-resident); den/acc in f64; msg f32.
// ---------------------------------------------------------------------------
__global__ __launch_bounds__(256) void gather_both(
    const int2* __restrict__ srtT, const int* __restrict__ ptr_r,
    const float* __restrict__ s_msg, float* __restrict__ msg_tgt,
    const int2* __restrict__ srtS, const int* __restrict__ ptr_c,
    const float* __restrict__ t_msg, float* __restrict__ msg_src,
    const double* __restrict__ es_d, const double* __restrict__ et_d)
{
    const int gw   = (blockIdx.x * blockDim.x + threadIdx.x) >> 6;
    const int lane = threadIdx.x & 63;

    const int2* srt; const int* ptr; const float* min_; float* out;
    const double* other_d; double base; int row;
    if (gw < N_TGT) {
        srt = srtT; ptr = ptr_r; min_ = s_msg; out = msg_tgt;
        other_d = es_d; row = gw; base = et_d[row];
    } else {
        row = gw - N_TGT;
        if (row >= N_SRC) return;
        srt = srtS; ptr = ptr_c; min_ = t_msg; out = msg_src;
        other_d = et_d; base = es_d[row];
    }

    const int b = ptr[row], e = ptr[row + 1];
    double den = 0.0, acc = 0.0;

    for (int j0 = b; j0 < e; j0 += 64) {
        const int m = e - j0;
        int oidx = 0; double v = 0.0; float wf = 0.f;
        if (lane < m) {
            const int2 pay = srt[j0 + lane];
            oidx = pay.x;
            const float nb = __int_as_float(pay.y);
            const double sv = base + other_d[oidx];
            v = (sv >= 0.0) ? sv : NEG * sv;
            wf = (float)(v * (double)nb);
        }
        den += v;

        const int cnt = m < 64 ? m : 64;
        for (int j = 0; j < cnt; ++j) {
            const int   c = __shfl(oidx, j);
            const float w = __shfl(wf, j);
            acc += (double)w * (double)min_[(size_t)c * 64 + lane];
        }
    }
    #pragma unroll
    for (int s = 32; s; s >>= 1) den += __shfl_xor(den, s);
    const double inv = (den != 0.0) ? 1.0 / den : 0.0;
    out[(size_t)row * 64 + lane] = (float)(acc * inv);
}

// ===========================================================================
extern "C" void kernel_launch(void* const* d_in, const int* in_sizes, int n_in,
                              void* d_out, int out_size, void* d_ws, size_t ws_size,
                              hipStream_t stream)
{
    const float* x_source = (const float*)d_in[0];
    const float* x_target = (const float*)d_in[1];
    const float* w_s      = (const float*)d_in[2];
    const float* w_t      = (const float*)d_in[3];
    const float* att      = (const float*)d_in[4];
    const float* nbhd     = (const float*)d_in[5];
    const int*   rows     = (const int*)d_in[6];
    const int*   cols     = (const int*)d_in[7];

    float* out     = (float*)d_out;
    float* msg_src = out;                       // (N_SRC, 64)
    float* msg_tgt = out + (size_t)N_SRC * 64;  // (N_TGT, 64)

    char* ws = (char*)d_ws;
    // byte layout: total 57,400,016 B
    float*  s_msg = (float*) (ws + 0);           // 25,600,000
    float*  t_msg = (float*) (ws + 25600000);    // 12,800,000
    double* es_d  = (double*)(ws + 38400000);    //    800,000
    double* et_d  = (double*)(ws + 39200000);    //    400,000
    int*    cnt_r = (int*)   (ws + 39600000);    //    200,000
    int*    cnt_c = (int*)   (ws + 39800000);    //    400,000
    int*    ptr_r = (int*)   (ws + 40200000);    //    200,004
    int*    ptr_c = (int*)   (ws + 40400004);    //    400,004
    int*    ofs_r = (int*)   (ws + 40800008);    //    200,000
    int*    ofs_c = (int*)   (ws + 41000008);    //    400,000 (+8 pad)
    unsigned long long* srtT = (unsigned long long*)(ws + 41400016); // 8,000,000
    unsigned long long* srtS = (unsigned long long*)(ws + 49400016); // 8,000,000

    hipMemsetAsync(ws + 39600000, 0, 600000, stream);  // cnt_r + cnt_c

    gemm_lds4<<<(N_SRC + 63) / 64, 256, 0, stream>>>(
        x_source, w_s, att, 0, N_SRC, s_msg, es_d);
    gemm_lds4<<<(N_TGT + 63) / 64, 256, 0, stream>>>(
        x_target, w_t, att, 64, N_TGT, t_msg, et_d);

    hist_part<<<2048, 256, 0, stream>>>(rows, cols, cnt_r, cnt_c);
    scan_two<<<2, 1024, 0, stream>>>(cnt_r, cnt_c, ptr_r, ofs_r, ptr_c, ofs_c);
    scatter_part<<<2048, 256, 0, stream>>>(
        rows, cols, nbhd, ofs_r, ofs_c, srtT, srtS);

    gather_both<<<(N_TGT + N_SRC + 3) / 4, 256, 0, stream>>>(
        (const int2*)srtT, ptr_r, s_msg, msg_tgt,
        (const int2*)srtS, ptr_c, t_msg, msg_src, es_d, et_d);
}

// Round 11
// 402.464 us; speedup vs baseline: 1.4847x; 1.4127x over previous
//
#include <hip/hip_runtime.h>

#define N_SRC   100000
#define N_TGT   50000
#define N_EDGES 1000000
#define NEG     0.2
#define NXCD    8
#define TPART   (N_TGT / NXCD)   // 6250
#define SPART   (N_SRC / NXCD)   // 12500

// ===========================================================================
// CSR/CSC build + gather. Edge-score math in f64 (ill-conditioned row sums);
// msg matrices f32 (bf16 fatal, R6). Scatter/hist XCD-partitioned (R8-proven).
// GEMM: 4 column-waves from one LDS x tile; c0 forced wave-uniform via
// readfirstlane so w loads become s_load (R9/R10: vector-load suspicion).
// Gather: 4-way accumulator split breaks the f64 dependency chain.
// ===========================================================================

// ---------------------------------------------------------------------------
#define XS 129
__global__ __launch_bounds__(256) void gemm_lds4(
    const float* __restrict__ x, const float* __restrict__ w,
    const float* __restrict__ att, int att_off, int nrows,
    float* __restrict__ msg, double* __restrict__ evec)
{
    __shared__ float xs[64 * XS];          // 33 KB
    __shared__ double eds[4][64];          //  2 KB
    const int tid  = threadIdx.x;
    const int lane = tid & 63;
    const int part = tid >> 6;             // 0..3, wave-uniform in fact
    const int c0   = __builtin_amdgcn_readfirstlane(part << 4);  // provably scalar
    const int row0 = blockIdx.x * 64;
    const int row  = row0 + lane;
    const bool act = row < nrows;

    // stage 64 rows x 128 f32: 2048 float4, 256 threads -> 8 iters, coalesced
    #pragma unroll
    for (int it = 0; it < 8; ++it) {
        const int fid = tid + it * 256;    // 0..2047
        const int r = fid >> 5, q = fid & 31;
        if (row0 + r < nrows) {
            const float4 v = *(const float4*)(x + (size_t)(row0 + r) * 128 + 4 * q);
            float* d = &xs[r * XS + 4 * q];
            d[0] = v.x; d[1] = v.y; d[2] = v.z; d[3] = v.w;
        }
    }
    __syncthreads();

    float acc[16];
    #pragma unroll
    for (int c = 0; c < 16; ++c) acc[c] = 0.f;

    const int xbase = lane * XS;
    for (int kc = 0; kc < 128; kc += 16) {     // 8 chunks
        #pragma unroll
        for (int kk = 0; kk < 16; ++kk) {
            const float xk = xs[xbase + kc + kk];
            const float* wr = w + (size_t)(kc + kk) * 64 + c0;  // scalar addr
            #pragma unroll
            for (int c = 0; c < 16; ++c)
                acc[c] = fmaf(xk, wr[c], acc[c]);
        }
    }

    // evec partial dot (f64), combine across parts in fixed order
    double e = 0.0;
    #pragma unroll
    for (int c = 0; c < 16; ++c)
        e += (double)acc[c] * (double)att[att_off + c0 + c];
    eds[part][lane] = e;
    __syncthreads();
    if (part == 0 && act)
        evec[row] = eds[0][lane] + eds[1][lane] + eds[2][lane] + eds[3][lane];

    if (act) {
        float* mo = msg + (size_t)row * 64 + c0;
        #pragma unroll
        for (int q = 0; q < 4; ++q)
            *(float4*)(mo + 4 * q) = *(float4*)(acc + 4 * q);
    }
}

// ---------------------------------------------------------------------------
// Histogram, XCD-partitioned (R8-proven).
// ---------------------------------------------------------------------------
__global__ __launch_bounds__(256) void hist_part(
    const int* __restrict__ rows, const int* __restrict__ cols,
    int* __restrict__ cnt_r, int* __restrict__ cnt_c)
{
    const int xcd  = blockIdx.x & (NXCD - 1);
    const int ibx  = blockIdx.x >> 3;
    const int step = (gridDim.x >> 3) * blockDim.x;
    const int lo_r = xcd * TPART, lo_c = xcd * SPART;

    for (int i = ibx * blockDim.x + threadIdx.x; i < N_EDGES; i += step) {
        const int r = rows[i], c = cols[i];
        if ((unsigned)(r - lo_r) < TPART) atomicAdd(&cnt_r[r], 1);
        if ((unsigned)(c - lo_c) < SPART) atomicAdd(&cnt_c[c], 1);
    }
}

// ---------------------------------------------------------------------------
// Exclusive scan, tiled + coalesced. block 0 -> rows (N_TGT), 1 -> cols (N_SRC).
// ---------------------------------------------------------------------------
__global__ __launch_bounds__(1024) void scan_two(
    const int* __restrict__ cnt_r, const int* __restrict__ cnt_c,
    int* __restrict__ ptr_r, int* __restrict__ ofs_r,
    int* __restrict__ ptr_c, int* __restrict__ ofs_c)
{
    const int n    = blockIdx.x ? N_SRC : N_TGT;
    const int* cnt = blockIdx.x ? cnt_c : cnt_r;
    int* ptr       = blockIdx.x ? ptr_c : ptr_r;
    int* ofs       = blockIdx.x ? ofs_c : ofs_r;
    const int tid  = threadIdx.x;
    const int lane = tid & 63, wid = tid >> 6;

    __shared__ int wsum[16];
    __shared__ int s_carry;
    if (tid == 0) s_carry = 0;
    __syncthreads();

    for (int base = 0; base < n; base += 4096) {
        const int idx = base + tid * 4;
        int4 v = make_int4(0, 0, 0, 0);
        if (idx + 3 < n) {
            v = *(const int4*)(cnt + idx);
        } else if (idx < n) {
            v.x = cnt[idx];
            if (idx + 1 < n) v.y = cnt[idx + 1];
            if (idx + 2 < n) v.z = cnt[idx + 2];
        }
        const int s = v.x + v.y + v.z + v.w;

        int p = s;
        #pragma unroll
        for (int d = 1; d < 64; d <<= 1) {
            int t = __shfl_up(p, d);
            if (lane >= d) p += t;
        }
        if (lane == 63) wsum[wid] = p;
        __syncthreads();
        if (tid == 0) {
            int a = 0;
            #pragma unroll
            for (int i = 0; i < 16; ++i) { int t = wsum[i]; wsum[i] = a; a += t; }
        }
        __syncthreads();

        int run = s_carry + wsum[wid] + (p - s);
        if (idx     < n) { ptr[idx]     = run; ofs[idx]     = run; } run += v.x;
        if (idx + 1 < n) { ptr[idx + 1] = run; ofs[idx + 1] = run; } run += v.y;
        if (idx + 2 < n) { ptr[idx + 2] = run; ofs[idx + 2] = run; } run += v.z;
        if (idx + 3 < n) { ptr[idx + 3] = run; ofs[idx + 3] = run; } run += v.w;

        __syncthreads();
        if (tid == 1023) s_carry = run;
        __syncthreads();
    }
    if (tid == 0) ptr[n] = s_carry;
}

// ---------------------------------------------------------------------------
// Scatter, XCD-partitioned (R8-proven: write-amp gone).
// ---------------------------------------------------------------------------
__global__ __launch_bounds__(256) void scatter_part(
    const int* __restrict__ rows, const int* __restrict__ cols,
    const float* __restrict__ nbhd,
    int* __restrict__ ofs_r, int* __restrict__ ofs_c,
    unsigned long long* __restrict__ srtT, unsigned long long* __restrict__ srtS)
{
    const int xcd  = blockIdx.x & (NXCD - 1);
    const int ibx  = blockIdx.x >> 3;
    const int step = (gridDim.x >> 3) * blockDim.x;
    const int lo_r = xcd * TPART, lo_c = xcd * SPART;

    for (int i = ibx * blockDim.x + threadIdx.x; i < N_EDGES; i += step) {
        const int r = rows[i], c = cols[i];
        const bool mr = (unsigned)(r - lo_r) < TPART;
        const bool mc = (unsigned)(c - lo_c) < SPART;
        if (!(mr | mc)) continue;
        const unsigned long long nb =
            (unsigned long long)(unsigned)__float_as_int(nbhd[i]) << 32;
        if (mr) { const int p = atomicAdd(&ofs_r[r], 1); srtT[p] = nb | (unsigned)c; }
        if (mc) { const int q = atomicAdd(&ofs_c[c], 1); srtS[q] = nb | (unsigned)r; }
    }
}

// ---------------------------------------------------------------------------
// Gather: one wave per output row, lane = feature. Scores recomputed in f64
// from es_d/et_d (L2-resident). acc split 4-way to break the f64 FMA chain
// and keep 4 gather loads in flight.
// ---------------------------------------------------------------------------
__global__ __launch_bounds__(256) void gather_both(
    const int2* __restrict__ srtT, const int* __restrict__ ptr_r,
    const float* __restrict__ s_msg, float* __restrict__ msg_tgt,
    const int2* __restrict__ srtS, const int* __restrict__ ptr_c,
    const float* __restrict__ t_msg, float* __restrict__ msg_src,
    const double* __restrict__ es_d, const double* __restrict__ et_d)
{
    const int gw   = (blockIdx.x * blockDim.x + threadIdx.x) >> 6;
    const int lane = threadIdx.x & 63;

    const int2* srt; const int* ptr; const float* min_; float* out;
    const double* other_d; double base; int row;
    if (gw < N_TGT) {
        srt = srtT; ptr = ptr_r; min_ = s_msg; out = msg_tgt;
        other_d = es_d; row = gw; base = et_d[row];
    } else {
        row = gw - N_TGT;
        if (row >= N_SRC) return;
        srt = srtS; ptr = ptr_c; min_ = t_msg; out = msg_src;
        other_d = et_d; base = es_d[row];
    }

    const int b = ptr[row], e = ptr[row + 1];
    double den = 0.0;
    double a0 = 0.0, a1 = 0.0, a2 = 0.0, a3 = 0.0;

    for (int j0 = b; j0 < e; j0 += 64) {
        const int m = e - j0;
        int oidx = 0; double v = 0.0; float wf = 0.f;
        if (lane < m) {
            const int2 pay = srt[j0 + lane];
            oidx = pay.x;
            const float nb = __int_as_float(pay.y);
            const double sv = base + other_d[oidx];
            v = (sv >= 0.0) ? sv : NEG * sv;
            wf = (float)(v * (double)nb);
        }
        den += v;

        const int cnt = m < 64 ? m : 64;
        int j = 0;
        for (; j + 3 < cnt; j += 4) {
            const int   c0_ = __shfl(oidx, j);     const float w0 = __shfl(wf, j);
            const int   c1_ = __shfl(oidx, j + 1); const float w1 = __shfl(wf, j + 1);
            const int   c2_ = __shfl(oidx, j + 2); const float w2 = __shfl(wf, j + 2);
            const int   c3_ = __shfl(oidx, j + 3); const float w3 = __shfl(wf, j + 3);
            a0 += (double)w0 * (double)min_[(size_t)c0_ * 64 + lane];
            a1 += (double)w1 * (double)min_[(size_t)c1_ * 64 + lane];
            a2 += (double)w2 * (double)min_[(size_t)c2_ * 64 + lane];
            a3 += (double)w3 * (double)min_[(size_t)c3_ * 64 + lane];
        }
        for (; j < cnt; ++j) {
            const int   c = __shfl(oidx, j);
            const float w = __shfl(wf, j);
            a0 += (double)w * (double)min_[(size_t)c * 64 + lane];
        }
    }
    #pragma unroll
    for (int s = 32; s; s >>= 1) den += __shfl_xor(den, s);
    const double inv = (den != 0.0) ? 1.0 / den : 0.0;
    const double acc = (a0 + a1) + (a2 + a3);
    out[(size_t)row * 64 + lane] = (float)(acc * inv);
}

// ===========================================================================
extern "C" void kernel_launch(void* const* d_in, const int* in_sizes, int n_in,
                              void* d_out, int out_size, void* d_ws, size_t ws_size,
                              hipStream_t stream)
{
    const float* x_source = (const float*)d_in[0];
    const float* x_target = (const float*)d_in[1];
    const float* w_s      = (const float*)d_in[2];
    const float* w_t      = (const float*)d_in[3];
    const float* att      = (const float*)d_in[4];
    const float* nbhd     = (const float*)d_in[5];
    const int*   rows     = (const int*)d_in[6];
    const int*   cols     = (const int*)d_in[7];

    float* out     = (float*)d_out;
    float* msg_src = out;                       // (N_SRC, 64)
    float* msg_tgt = out + (size_t)N_SRC * 64;  // (N_TGT, 64)

    char* ws = (char*)d_ws;
    // byte layout: total 57,400,016 B
    float*  s_msg = (float*) (ws + 0);           // 25,600,000
    float*  t_msg = (float*) (ws + 25600000);    // 12,800,000
    double* es_d  = (double*)(ws + 38400000);    //    800,000
    double* et_d  = (double*)(ws + 39200000);    //    400,000
    int*    cnt_r = (int*)   (ws + 39600000);    //    200,000
    int*    cnt_c = (int*)   (ws + 39800000);    //    400,000
    int*    ptr_r = (int*)   (ws + 40200000);    //    200,004
    int*    ptr_c = (int*)   (ws + 40400004);    //    400,004
    int*    ofs_r = (int*)   (ws + 40800008);    //    200,000
    int*    ofs_c = (int*)   (ws + 41000008);    //    400,000 (+8 pad)
    unsigned long long* srtT = (unsigned long long*)(ws + 41400016); // 8,000,000
    unsigned long long* srtS = (unsigned long long*)(ws + 49400016); // 8,000,000

    hipMemsetAsync(ws + 39600000, 0, 600000, stream);  // cnt_r + cnt_c

    gemm_lds4<<<(N_SRC + 63) / 64, 256, 0, stream>>>(
        x_source, w_s, att, 0, N_SRC, s_msg, es_d);
    gemm_lds4<<<(N_TGT + 63) / 64, 256, 0, stream>>>(
        x_target, w_t, att, 64, N_TGT, t_msg, et_d);

    hist_part<<<2048, 256, 0, stream>>>(rows, cols, cnt_r, cnt_c);
    scan_two<<<2, 1024, 0, stream>>>(cnt_r, cnt_c, ptr_r, ofs_r, ptr_c, ofs_c);
    scatter_part<<<2048, 256, 0, stream>>>(
        rows, cols, nbhd, ofs_r, ofs_c, srtT, srtS);

    gather_both<<<(N_TGT + N_SRC + 3) / 4, 256, 0, stream>>>(
        (const int2*)srtT, ptr_r, s_msg, msg_tgt,
        (const int2*)srtS, ptr_c, t_msg, msg_src, es_d, et_d);
}

// Round 12
// 332.870 us; speedup vs baseline: 1.7951x; 1.2091x over previous
//
#include <hip/hip_runtime.h>

#define N_SRC   100000
#define N_TGT   50000
#define N_EDGES 1000000
#define NEG     0.2
#define NXCD    8
#define TPART   (N_TGT / NXCD)   // 6250
#define SPART   (N_SRC / NXCD)   // 12500

// ===========================================================================
// CSR/CSC build + gather. Edge-score math in f64 (ill-conditioned row sums);
// msg matrices f32 (bf16 fatal, R6). R8: XCD-partitioned scatter (write-amp
// fix). R11: readfirstlane GEMM + ILP gather. R12: rank-based scatter — the
// per-edge slot is assigned in the hist pass (sequential rank writes), so the
// scatter pass has NO atomics.
// ===========================================================================

// ---------------------------------------------------------------------------
// GEMM: 64 rows x 4 col-waves per block, x staged in LDS, w via s_load
// (c0 forced scalar with readfirstlane — R11-proven). acc[16]/lane.
// ---------------------------------------------------------------------------
#define XS 129
__global__ __launch_bounds__(256) void gemm_lds4(
    const float* __restrict__ x, const float* __restrict__ w,
    const float* __restrict__ att, int att_off, int nrows,
    float* __restrict__ msg, double* __restrict__ evec)
{
    __shared__ float xs[64 * XS];          // 33 KB
    __shared__ double eds[4][64];          //  2 KB
    const int tid  = threadIdx.x;
    const int lane = tid & 63;
    const int part = tid >> 6;
    const int c0   = __builtin_amdgcn_readfirstlane(part << 4);
    const int row0 = blockIdx.x * 64;
    const int row  = row0 + lane;
    const bool act = row < nrows;

    #pragma unroll
    for (int it = 0; it < 8; ++it) {
        const int fid = tid + it * 256;
        const int r = fid >> 5, q = fid & 31;
        if (row0 + r < nrows) {
            const float4 v = *(const float4*)(x + (size_t)(row0 + r) * 128 + 4 * q);
            float* d = &xs[r * XS + 4 * q];
            d[0] = v.x; d[1] = v.y; d[2] = v.z; d[3] = v.w;
        }
    }
    __syncthreads();

    float acc[16];
    #pragma unroll
    for (int c = 0; c < 16; ++c) acc[c] = 0.f;

    const int xbase = lane * XS;
    for (int kc = 0; kc < 128; kc += 16) {
        #pragma unroll
        for (int kk = 0; kk < 16; ++kk) {
            const float xk = xs[xbase + kc + kk];
            const float* wr = w + (size_t)(kc + kk) * 64 + c0;  // scalar addr
            #pragma unroll
            for (int c = 0; c < 16; ++c)
                acc[c] = fmaf(xk, wr[c], acc[c]);
        }
    }

    double e = 0.0;
    #pragma unroll
    for (int c = 0; c < 16; ++c)
        e += (double)acc[c] * (double)att[att_off + c0 + c];
    eds[part][lane] = e;
    __syncthreads();
    if (part == 0 && act)
        evec[row] = eds[0][lane] + eds[1][lane] + eds[2][lane] + eds[3][lane];

    if (act) {
        float* mo = msg + (size_t)row * 64 + c0;
        #pragma unroll
        for (int q = 0; q < 4; ++q)
            *(float4*)(mo + 4 * q) = *(float4*)(acc + 4 * q);
    }
}

// ---------------------------------------------------------------------------
// Histogram + rank assignment (unpartitioned, one thread per edge).
// rank writes are sequential full-line stores; cnt atomics bounce across
// XCDs but are only ~65 us (R4/R5 evidence).
// ---------------------------------------------------------------------------
__global__ __launch_bounds__(256) void hist_rank(
    const int* __restrict__ rows, const int* __restrict__ cols,
    int* __restrict__ cnt_r, int* __restrict__ cnt_c,
    int* __restrict__ rank_r, int* __restrict__ rank_c)
{
    const int i = blockIdx.x * blockDim.x + threadIdx.x;
    if (i >= N_EDGES) return;
    rank_r[i] = atomicAdd(&cnt_r[rows[i]], 1);
    rank_c[i] = atomicAdd(&cnt_c[cols[i]], 1);
}

// ---------------------------------------------------------------------------
// Exclusive scan, tiled + coalesced. block 0 -> rows (N_TGT), 1 -> cols (N_SRC).
// ---------------------------------------------------------------------------
__global__ __launch_bounds__(1024) void scan_two(
    const int* __restrict__ cnt_r, const int* __restrict__ cnt_c,
    int* __restrict__ ptr_r, int* __restrict__ ptr_c)
{
    const int n    = blockIdx.x ? N_SRC : N_TGT;
    const int* cnt = blockIdx.x ? cnt_c : cnt_r;
    int* ptr       = blockIdx.x ? ptr_c : ptr_r;
    const int tid  = threadIdx.x;
    const int lane = tid & 63, wid = tid >> 6;

    __shared__ int wsum[16];
    __shared__ int s_carry;
    if (tid == 0) s_carry = 0;
    __syncthreads();

    for (int base = 0; base < n; base += 4096) {
        const int idx = base + tid * 4;
        int4 v = make_int4(0, 0, 0, 0);
        if (idx + 3 < n) {
            v = *(const int4*)(cnt + idx);
        } else if (idx < n) {
            v.x = cnt[idx];
            if (idx + 1 < n) v.y = cnt[idx + 1];
            if (idx + 2 < n) v.z = cnt[idx + 2];
        }
        const int s = v.x + v.y + v.z + v.w;

        int p = s;
        #pragma unroll
        for (int d = 1; d < 64; d <<= 1) {
            int t = __shfl_up(p, d);
            if (lane >= d) p += t;
        }
        if (lane == 63) wsum[wid] = p;
        __syncthreads();
        if (tid == 0) {
            int a = 0;
            #pragma unroll
            for (int i = 0; i < 16; ++i) { int t = wsum[i]; wsum[i] = a; a += t; }
        }
        __syncthreads();

        int run = s_carry + wsum[wid] + (p - s);
        if (idx     < n) ptr[idx]     = run; run += v.x;
        if (idx + 1 < n) ptr[idx + 1] = run; run += v.y;
        if (idx + 2 < n) ptr[idx + 2] = run; run += v.z;
        if (idx + 3 < n) ptr[idx + 3] = run; run += v.w;

        __syncthreads();
        if (tid == 1023) s_carry = run;
        __syncthreads();
    }
    if (tid == 0) ptr[n] = s_carry;
}

// ---------------------------------------------------------------------------
// Scatter, XCD-partitioned (write locality, R8) and ATOMIC-FREE (R12):
// slot = ptr[node] + rank[i], with rank from hist_rank.
// ---------------------------------------------------------------------------
__global__ __launch_bounds__(256) void scatter_part(
    const int* __restrict__ rows, const int* __restrict__ cols,
    const float* __restrict__ nbhd,
    const int* __restrict__ ptr_r, const int* __restrict__ ptr_c,
    const int* __restrict__ rank_r, const int* __restrict__ rank_c,
    unsigned long long* __restrict__ srtT, unsigned long long* __restrict__ srtS)
{
    const int xcd  = blockIdx.x & (NXCD - 1);
    const int ibx  = blockIdx.x >> 3;
    const int step = (gridDim.x >> 3) * blockDim.x;
    const int lo_r = xcd * TPART, lo_c = xcd * SPART;

    for (int i = ibx * blockDim.x + threadIdx.x; i < N_EDGES; i += step) {
        const int r = rows[i], c = cols[i];
        const bool mr = (unsigned)(r - lo_r) < TPART;
        const bool mc = (unsigned)(c - lo_c) < SPART;
        if (!(mr | mc)) continue;
        const unsigned long long nb =
            (unsigned long long)(unsigned)__float_as_int(nbhd[i]) << 32;
        if (mr) srtT[ptr_r[r] + rank_r[i]] = nb | (unsigned)c;
        if (mc) srtS[ptr_c[c] + rank_c[i]] = nb | (unsigned)r;
    }
}

// ---------------------------------------------------------------------------
// Gather: one wave per output row, lane = feature. Scores in f64 from
// es_d/et_d; 4-way acc split for ILP (R11-proven).
// ---------------------------------------------------------------------------
__global__ __launch_bounds__(256) void gather_both(
    const int2* __restrict__ srtT, const int* __restrict__ ptr_r,
    const float* __restrict__ s_msg, float* __restrict__ msg_tgt,
    const int2* __restrict__ srtS, const int* __restrict__ ptr_c,
    const float* __restrict__ t_msg, float* __restrict__ msg_src,
    const double* __restrict__ es_d, const double* __restrict__ et_d)
{
    const int gw   = (blockIdx.x * blockDim.x + threadIdx.x) >> 6;
    const int lane = threadIdx.x & 63;

    const int2* srt; const int* ptr; const float* min_; float* out;
    const double* other_d; double base; int row;
    if (gw < N_TGT) {
        srt = srtT; ptr = ptr_r; min_ = s_msg; out = msg_tgt;
        other_d = es_d; row = gw; base = et_d[row];
    } else {
        row = gw - N_TGT;
        if (row >= N_SRC) return;
        srt = srtS; ptr = ptr_c; min_ = t_msg; out = msg_src;
        other_d = et_d; base = es_d[row];
    }

    const int b = ptr[row], e = ptr[row + 1];
    double den = 0.0;
    double a0 = 0.0, a1 = 0.0, a2 = 0.0, a3 = 0.0;

    for (int j0 = b; j0 < e; j0 += 64) {
        const int m = e - j0;
        int oidx = 0; double v = 0.0; float wf = 0.f;
        if (lane < m) {
            const int2 pay = srt[j0 + lane];
            oidx = pay.x;
            const float nb = __int_as_float(pay.y);
            const double sv = base + other_d[oidx];
            v = (sv >= 0.0) ? sv : NEG * sv;
            wf = (float)(v * (double)nb);
        }
        den += v;

        const int cnt = m < 64 ? m : 64;
        int j = 0;
        for (; j + 3 < cnt; j += 4) {
            const int   c0_ = __shfl(oidx, j);     const float w0 = __shfl(wf, j);
            const int   c1_ = __shfl(oidx, j + 1); const float w1 = __shfl(wf, j + 1);
            const int   c2_ = __shfl(oidx, j + 2); const float w2 = __shfl(wf, j + 2);
            const int   c3_ = __shfl(oidx, j + 3); const float w3 = __shfl(wf, j + 3);
            a0 += (double)w0 * (double)min_[(size_t)c0_ * 64 + lane];
            a1 += (double)w1 * (double)min_[(size_t)c1_ * 64 + lane];
            a2 += (double)w2 * (double)min_[(size_t)c2_ * 64 + lane];
            a3 += (double)w3 * (double)min_[(size_t)c3_ * 64 + lane];
        }
        for (; j < cnt; ++j) {
            const int   c = __shfl(oidx, j);
            const float w = __shfl(wf, j);
            a0 += (double)w * (double)min_[(size_t)c * 64 + lane];
        }
    }
    #pragma unroll
    for (int s = 32; s; s >>= 1) den += __shfl_xor(den, s);
    const double inv = (den != 0.0) ? 1.0 / den : 0.0;
    const double acc = (a0 + a1) + (a2 + a3);
    out[(size_t)row * 64 + lane] = (float)(acc * inv);
}

// ===========================================================================
extern "C" void kernel_launch(void* const* d_in, const int* in_sizes, int n_in,
                              void* d_out, int out_size, void* d_ws, size_t ws_size,
                              hipStream_t stream)
{
    const float* x_source = (const float*)d_in[0];
    const float* x_target = (const float*)d_in[1];
    const float* w_s      = (const float*)d_in[2];
    const float* w_t      = (const float*)d_in[3];
    const float* att      = (const float*)d_in[4];
    const float* nbhd     = (const float*)d_in[5];
    const int*   rows     = (const int*)d_in[6];
    const int*   cols     = (const int*)d_in[7];

    float* out     = (float*)d_out;
    float* msg_src = out;                       // (N_SRC, 64)
    float* msg_tgt = out + (size_t)N_SRC * 64;  // (N_TGT, 64)

    char* ws = (char*)d_ws;
    // byte layout: total 65,400,016 B
    float*  s_msg  = (float*) (ws + 0);           // 25,600,000
    float*  t_msg  = (float*) (ws + 25600000);    // 12,800,000
    double* es_d   = (double*)(ws + 38400000);    //    800,000
    double* et_d   = (double*)(ws + 39200000);    //    400,000
    int*    cnt_r  = (int*)   (ws + 39600000);    //    200,000
    int*    cnt_c  = (int*)   (ws + 39800000);    //    400,000
    int*    ptr_r  = (int*)   (ws + 40200000);    //    200,004
    int*    ptr_c  = (int*)   (ws + 40400004);    //    400,004 (+8 pad)
    int*    rank_r = (int*)   (ws + 40800016);    //  4,000,000
    int*    rank_c = (int*)   (ws + 44800016);    //  4,000,000
    unsigned long long* srtT = (unsigned long long*)(ws + 48800016); // 8,000,000
    unsigned long long* srtS = (unsigned long long*)(ws + 56800016); // 8,000,000

    hipMemsetAsync(ws + 39600000, 0, 600000, stream);  // cnt_r + cnt_c

    gemm_lds4<<<(N_SRC + 63) / 64, 256, 0, stream>>>(
        x_source, w_s, att, 0, N_SRC, s_msg, es_d);
    gemm_lds4<<<(N_TGT + 63) / 64, 256, 0, stream>>>(
        x_target, w_t, att, 64, N_TGT, t_msg, et_d);

    hist_rank<<<(N_EDGES + 255) / 256, 256, 0, stream>>>(
        rows, cols, cnt_r, cnt_c, rank_r, rank_c);
    scan_two<<<2, 1024, 0, stream>>>(cnt_r, cnt_c, ptr_r, ptr_c);
    scatter_part<<<2048, 256, 0, stream>>>(
        rows, cols, nbhd, ptr_r, ptr_c, rank_r, rank_c, srtT, srtS);

    gather_both<<<(N_TGT + N_SRC + 3) / 4, 256, 0, stream>>>(
        (const int2*)srtT, ptr_r, s_msg, msg_tgt,
        (const int2*)srtS, ptr_c, t_msg, msg_src, es_d, et_d);
}